// Round 6
// baseline (364.704 us; speedup 1.0000x reference)
//
#include <hip/hip_runtime.h>
#include <hip/hip_bf16.h>
#include <math.h>

#ifndef M_PI_F
#define M_PI_F 3.14159265358979323846f
#endif

static constexpr int Bb = 2, Tt = 1024, Dd = 1024, Hh = 16, DHh = 64, NFf = 256, Rr = 4096;
static constexpr int Mm = Bb * Tt;
static constexpr int CHK = 64, NCHK = Tt / CHK;  // attention chunking
static constexpr int QS = 3072;                  // fused qkv row stride

enum Epi { EPI_NONE = 0, EPI_RELU, EPI_QKV, EPI_AMPPHI };

typedef __attribute__((ext_vector_type(8))) short bf16x8;
typedef __attribute__((ext_vector_type(4))) float f32x4;

// ---------------------------------------------------------------------------
// async global->LDS, 16B per lane. LDS dest is wave-uniform base; HW adds
// lane*16. Global address is per-lane.
// ---------------------------------------------------------------------------
__device__ inline void gload16(const short* g, short* l) {
  __builtin_amdgcn_global_load_lds(
      (const __attribute__((address_space(1))) unsigned int*)g,
      (__attribute__((address_space(3))) unsigned int*)l, 16, 0, 0);
}

// ---------------------------------------------------------------------------
// bf16 MFMA GEMM: C[M,N] = epi(A[M,K] @ BT[N,K]^T + bias)
// 128x128 tile, BK=64, 4 waves (2x2), each 64x64 via 4x4 frags of 16x16x32.
// - LDS XOR bank-swizzle (rule #21 both-sides involution): gload_lds dest
//   linear, global SOURCE pre-permuted (skk), ds_read applies same XOR.
// - Bijective XCD swizzle (m204) for A-panel L2 reuse per XCD.
// - SPLITK (=#slices): blockIdx.z selects K-slice, writes fp32 partial at
//   Cf + z*M*N (no epilogue). Partial buffer placement is the CALLER's
//   responsibility — must not overlap A or BT (r4 had such a race).
// ---------------------------------------------------------------------------
template <int EPI, int OUTBF, int SPLITK>
__global__ __launch_bounds__(256) void gemm_mfma(const short* __restrict__ A,
                                                 const short* __restrict__ BT,
                                                 const float* __restrict__ bias,
                                                 const float* __restrict__ bias2,
                                                 float* __restrict__ Cf,
                                                 float* __restrict__ Cf2,
                                                 __hip_bfloat16* __restrict__ Cb,
                                                 int M, int N, int ldk) {
  __shared__ short lA[128 * 64];
  __shared__ short lB[128 * 64];
  const int tid = threadIdx.x;
  const int wid = tid >> 6, lane = tid & 63;

  // XCD-aware bijective block swizzle (grids here always have nwg % 8 == 0)
  const int nwg = gridDim.x * gridDim.y;
  const int wg = blockIdx.y * gridDim.x + blockIdx.x;
  const int qq = nwg >> 3, rr = nwg & 7;
  const int xcd = wg & 7, idx = wg >> 3;
  const int wg2 = (xcd < rr ? xcd * (qq + 1) : rr * (qq + 1) + (xcd - rr) * qq) + idx;
  const int bx = wg2 % gridDim.x, by = wg2 / gridDim.x;

  const int m0 = by * 128, n0 = bx * 128;
  const int wm = (wid >> 1) * 64, wn = (wid & 1) * 64;
  const int srow = lane >> 3;                            // row within 8-row slab
  const int skk = (((lane & 7) ^ (lane >> 3)) << 3);     // swizzled k offset (elems)

  int kstart = 0, klen = ldk;
  if (SPLITK > 1) {
    klen = ldk / SPLITK;
    kstart = blockIdx.z * klen;
    Cf += (size_t)blockIdx.z * M * N;
  }

  f32x4 acc[4][4] = {};

  for (int k0 = kstart; k0 < kstart + klen; k0 += 64) {
#pragma unroll
    for (int si = 0; si < 4; ++si) {
      const int s = wid + si * 4;  // stage instruction index 0..15
      gload16(A + (size_t)(m0 + s * 8 + srow) * ldk + k0 + skk, &lA[s * 512]);
      gload16(BT + (size_t)(n0 + s * 8 + srow) * ldk + k0 + skk, &lB[s * 512]);
    }
    __syncthreads();  // drains vmcnt -> LDS tiles ready
#pragma unroll
    for (int kk = 0; kk < 2; ++kk) {
      const int krd = kk * 32 + (lane >> 4) * 8;
      const int rsel = lane & 15;
      const int kswz = krd ^ ((rsel & 7) << 3);  // same involution as store side
      bf16x8 af[4], bfr[4];
#pragma unroll
      for (int i = 0; i < 4; ++i) {
        af[i] = *(const bf16x8*)&lA[(wm + i * 16 + rsel) * 64 + kswz];
        bfr[i] = *(const bf16x8*)&lB[(wn + i * 16 + rsel) * 64 + kswz];
      }
#pragma unroll
      for (int i = 0; i < 4; ++i)
#pragma unroll
        for (int j = 0; j < 4; ++j)
          acc[i][j] = __builtin_amdgcn_mfma_f32_16x16x32_bf16(af[i], bfr[j], acc[i][j], 0, 0, 0);
    }
    __syncthreads();  // compute done before restage
  }

  const int crow = (lane >> 4) * 4;
  const int ccol = lane & 15;
#pragma unroll
  for (int j = 0; j < 4; ++j) {
    const int col = n0 + wn + j * 16 + ccol;
    float bv = 0.f;
    if (EPI == EPI_AMPPHI) {
      bv = (col < NFf) ? bias[col] : bias2[col - NFf];
    } else if (bias) {
      bv = bias[col];
    }
#pragma unroll
    for (int i = 0; i < 4; ++i) {
#pragma unroll
      for (int r = 0; r < 4; ++r) {
        float v = acc[i][j][r] + bv;
        const int row = m0 + wm + i * 16 + crow + r;
        if (EPI == EPI_AMPPHI) {
          if (col < NFf) {
            v = (v > 0.f) ? (v + log1pf(expf(-v))) : log1pf(expf(v));  // softplus
            Cf[(size_t)row * NFf + col] = v;
          } else {
            Cf2[(size_t)row * NFf + (col - NFf)] = M_PI_F * tanhf(v);
          }
        } else if (EPI == EPI_QKV) {
          Cf[(size_t)row * QS + col] = (col < 2048) ? fmaxf(v, 0.f) : v;
        } else {
          if (EPI == EPI_RELU) v = fmaxf(v, 0.f);
          const size_t off = (size_t)row * N + col;
          if (OUTBF)
            Cb[off] = __float2bfloat16(v);
          else
            Cf[off] = v;
        }
      }
    }
  }
}

// ---------------------------------------------------------------------------
// Fused transpose-cast of all 8 weight matrices: W[K,N] f32 -> WT[N,K] bf16.
// ---------------------------------------------------------------------------
struct TCDesc {
  const float* src[8];
  __hip_bfloat16* dst[8];
};

__global__ __launch_bounds__(256) void transpose_cast_all(TCDesc d) {
  constexpr int KS[8] = {1024, 1024, 768, 1024, 1024, 1024, 1024, 4096};
  constexpr int NS[8] = {256, 256, 1024, 1024, 1024, 1024, 4096, 1024};
  constexpr int CUM[9] = {0, 256, 512, 1280, 2304, 3328, 4352, 8448, 12544};
  __shared__ float tile[32][33];
  const int bid = blockIdx.x;
  int w = 0;
#pragma unroll
  for (int i = 0; i < 8; ++i)
    if (bid >= CUM[i + 1]) w = i + 1;
  const int tlocal = bid - CUM[w];
  const int K = KS[w], N = NS[w];
  const int tilesN = N / 32;
  const int bk = (tlocal / tilesN) * 32, bn = (tlocal % tilesN) * 32;
  const float* W = d.src[w];
  __hip_bfloat16* WT = d.dst[w];
  const int tx = threadIdx.x & 31, ty = threadIdx.x >> 5;  // 32x8
#pragma unroll
  for (int r = 0; r < 32; r += 8) tile[ty + r][tx] = W[(size_t)(bk + ty + r) * N + bn + tx];
  __syncthreads();
#pragma unroll
  for (int r = 0; r < 32; r += 8)
    WT[(size_t)(bn + ty + r) * K + bk + tx] = __float2bfloat16(tile[tx][ty + r]);
}

// ---------------------------------------------------------------------------
// x: f32 -> bf16 cast (row-major, layout preserved)
// ---------------------------------------------------------------------------
__global__ __launch_bounds__(256) void cast_x(const float* __restrict__ x,
                                              __hip_bfloat16* __restrict__ xb) {
  const int i = (blockIdx.x * 256 + threadIdx.x) * 4;
  const float4 v = *(const float4*)&x[i];
  xb[i + 0] = __float2bfloat16(v.x);
  xb[i + 1] = __float2bfloat16(v.y);
  xb[i + 2] = __float2bfloat16(v.z);
  xb[i + 3] = __float2bfloat16(v.w);
}

// ---------------------------------------------------------------------------
// polar -> cartesian, fp32 (amp,phi) -> bf16 (amp*cos, amp*sin).
// bf16 output halves the resonator scan's read traffic (scan is the
// per-CU-BW-bound kernel, r5 post-mortem).
// ---------------------------------------------------------------------------
__global__ __launch_bounds__(256) void polar_kernel(const float* __restrict__ a,
                                                    const float* __restrict__ p,
                                                    __hip_bfloat16* __restrict__ outr,
                                                    __hip_bfloat16* __restrict__ outi) {
  const int i = blockIdx.x * 256 + threadIdx.x;
  const float am = a[i], ph = p[i];
  float s, c;
  sincosf(ph, &s, &c);
  outr[i] = __float2bfloat16(am * c);
  outi[i] = __float2bfloat16(am * s);
}

// ---------------------------------------------------------------------------
// Sequential complex resonator recurrence; writes feat bf16 [B,T,3*NF].
// 16 blocks x 32 lanes: spreads the ~5 MB of traffic over 16 CUs (scan was
// per-CU-VMEM-bound at 8 CUs, r5). bf16 inputs halve read bytes. Register
// double-buffer (P=16) hides memory latency under the serial ALU chain.
// ---------------------------------------------------------------------------
static constexpr int RES_P = 16;

#define RES_LOAD(buf_r, buf_i, tg)                                        \
  if ((tg) < Tt) {                                                        \
    _Pragma("unroll") for (int i = 0; i < RES_P; ++i) {                   \
      buf_r[i] = __bfloat162float(ur[bbase + (size_t)((tg) + i) * NFf]);  \
      buf_i[i] = __bfloat162float(ui[bbase + (size_t)((tg) + i) * NFf]);  \
    }                                                                     \
  }

#define RES_STEP(buf_r, buf_i, tg)                              \
  _Pragma("unroll") for (int i = 0; i < RES_P; ++i) {           \
    const float pr = fmaf(ar, Xr, fmaf(-ai, Xi, buf_r[i]));     \
    const float pim = fmaf(ar, Xi, fmaf(ai, Xr, buf_i[i]));     \
    const float mag = __builtin_amdgcn_sqrtf(fmaf(pr, pr, pim * pim)); \
    const float g = __builtin_amdgcn_rcpf(1.f + __expf(th - mag));     \
    Xr = pr * g;                                                \
    Xi = pim * g;                                               \
    const size_t fb = ((size_t)b * Tt + (tg) + i) * (3 * NFf);  \
    featb[fb + f] = __float2bfloat16(Xr);                       \
    featb[fb + NFf + f] = __float2bfloat16(Xi);                 \
    featb[fb + 2 * NFf + f] = __float2bfloat16(mag * g);        \
  }

__global__ __launch_bounds__(32) void resonator_scan(const __hip_bfloat16* __restrict__ ur,
                                                     const __hip_bfloat16* __restrict__ ui,
                                                     const float* __restrict__ omega,
                                                     const float* __restrict__ ret_logit,
                                                     const float* __restrict__ theta,
                                                     __hip_bfloat16* __restrict__ featb) {
  const int b = blockIdx.x >> 3;                      // 16 blocks: B=2 x 8 slices
  const int f = (blockIdx.x & 7) * 32 + threadIdx.x;  // 32-freq slice
  const float dec = 1.f / (1.f + __expf(-ret_logit[f]));
  float so, co;
  sincosf(omega[f], &so, &co);
  const float ar = dec * co, ai = dec * so;
  const float th = theta[f];
  const size_t bbase = (size_t)b * Tt * NFf + f;
  float Xr = 0.f, Xi = 0.f;
  float Ar[RES_P], Ai[RES_P], Br[RES_P], Bi[RES_P];
  RES_LOAD(Ar, Ai, 0);
  for (int t0 = 0; t0 < Tt; t0 += 2 * RES_P) {
    RES_LOAD(Br, Bi, t0 + RES_P);
    RES_STEP(Ar, Ai, t0);
    RES_LOAD(Ar, Ai, t0 + 2 * RES_P);
    RES_STEP(Br, Bi, t0 + RES_P);
  }
}

// ---------------------------------------------------------------------------
// Attention phase A: per-chunk KV outer-product sums and k-sums.
// q/k/v live in the fused qkv buffer (row stride QS=3072).
// ---------------------------------------------------------------------------
__global__ __launch_bounds__(256) void attn_chunk_kv(const float* __restrict__ k,
                                                     const float* __restrict__ v,
                                                     float* __restrict__ S,
                                                     float* __restrict__ Ksum) {
  __shared__ float Ks[64][68], Vs[64][68];
  const int g = blockIdx.x;
  const int j = g & (NCHK - 1), bh = g >> 4;
  const int b = bh >> 4, h = bh & (Hh - 1);
  const int tid = threadIdx.x;
  const size_t rowbase = (size_t)(b * Tt + j * CHK) * QS + h * DHh;
  for (int l = tid; l < 4096; l += 256) {
    const int s = l >> 6, d = l & 63;
    Ks[s][d] = k[rowbase + (size_t)s * QS + d];
    Vs[s][d] = v[rowbase + (size_t)s * QS + d];
  }
  __syncthreads();
  const int d0 = tid & 63, eb = tid >> 6, e0 = eb * 16;
  float4 acc4[4] = {};
  float ks = 0.f;
  for (int s = 0; s < 64; ++s) {
    const float kd = Ks[s][d0];
    ks += kd;
#pragma unroll
    for (int i = 0; i < 4; ++i) {
      const float4 v4 = *(const float4*)&Vs[s][e0 + 4 * i];
      acc4[i].x = fmaf(kd, v4.x, acc4[i].x);
      acc4[i].y = fmaf(kd, v4.y, acc4[i].y);
      acc4[i].z = fmaf(kd, v4.z, acc4[i].z);
      acc4[i].w = fmaf(kd, v4.w, acc4[i].w);
    }
  }
  float* Sg = S + (size_t)g * 4096 + (size_t)d0 * 64 + e0;
#pragma unroll
  for (int i = 0; i < 4; ++i) *(float4*)&Sg[4 * i] = acc4[i];
  if (eb == 0) Ksum[(size_t)g * 64 + d0] = ks;
}

// ---------------------------------------------------------------------------
// Attention phase B: in-place EXCLUSIVE prefix over the 16 chunks per (b,h).
// ---------------------------------------------------------------------------
__global__ __launch_bounds__(256) void attn_prefix(float* __restrict__ S,
                                                   float* __restrict__ Ksum) {
  const int bh = blockIdx.x;
  const int tid = threadIdx.x;
  for (int r = 0; r < 16; ++r) {
    const int de = r * 256 + tid;
    float run = 0.f;
    size_t p = (size_t)bh * (NCHK * 4096) + de;
    for (int j = 0; j < NCHK; ++j, p += 4096) {
      const float tmp = S[p];
      S[p] = run;
      run += tmp;
    }
  }
  if (tid < 64) {
    float run = 0.f;
    size_t p = (size_t)bh * (NCHK * 64) + tid;
    for (int j = 0; j < NCHK; ++j, p += 64) {
      const float tmp = Ksum[p];
      Ksum[p] = run;
      run += tmp;
    }
  }
}

// ---------------------------------------------------------------------------
// Attention phase C: per-chunk output (q/k/v strided QS; y is [B,T,H,DH]).
// ---------------------------------------------------------------------------
__global__ __launch_bounds__(256) void attn_out(const float* __restrict__ q,
                                                const float* __restrict__ k,
                                                const float* __restrict__ v,
                                                const float* __restrict__ S,
                                                const float* __restrict__ Ksum,
                                                float* __restrict__ y) {
  __shared__ float Qt[64][65];
  __shared__ float KVP[64][68];
  __shared__ float At[64][65];
  const int g = blockIdx.x;
  const int j = g & (NCHK - 1), bh = g >> 4;
  const int b = bh >> 4, h = bh & (Hh - 1);
  const int tid = threadIdx.x;
  const size_t rowbase = (size_t)(b * Tt + j * CHK) * QS + h * DHh;
  const size_t ybase = (((size_t)b * Tt + j * CHK) * Hh + h) * DHh;
  for (int l = tid; l < 4096; l += 256) {
    const int s = l >> 6, d = l & 63;
    Qt[d][s] = q[rowbase + (size_t)s * QS + d];
    KVP[s][d] = k[rowbase + (size_t)s * QS + d];
  }
  __syncthreads();
  const int t = tid >> 2, sg = tid & 3;
  const float* pk = Ksum + (size_t)g * 64;
  // --- stage 1: masked scores + denominator ---
  float adot[16] = {};
  float qpk = 0.f;
  for (int c = 0; c < 16; ++c) {
    const float q0 = Qt[4 * c + 0][t], q1 = Qt[4 * c + 1][t];
    const float q2 = Qt[4 * c + 2][t], q3 = Qt[4 * c + 3][t];
    const float4 pk4 = *(const float4*)&pk[4 * c];
    qpk = fmaf(q0, pk4.x, fmaf(q1, pk4.y, fmaf(q2, pk4.z, fmaf(q3, pk4.w, qpk))));
#pragma unroll
    for (int i = 0; i < 16; ++i) {
      const float4 k4 = *(const float4*)&KVP[sg * 16 + i][4 * c];
      adot[i] = fmaf(q0, k4.x, fmaf(q1, k4.y, fmaf(q2, k4.z, fmaf(q3, k4.w, adot[i]))));
    }
  }
  float rs = 0.f;
#pragma unroll
  for (int i = 0; i < 16; ++i) {
    if (sg * 16 + i > t) adot[i] = 0.f;
    rs += adot[i];
  }
  rs += __shfl_xor(rs, 1);
  rs += __shfl_xor(rs, 2);
  const float den = qpk + rs + 1e-6f;
  __syncthreads();  // all K reads complete
#pragma unroll
  for (int i = 0; i < 16; ++i) At[sg * 16 + i][t] = adot[i];
  for (int l = tid; l < 4096; l += 256) {  // overwrite K with V
    const int s = l >> 6, d = l & 63;
    KVP[s][d] = v[rowbase + (size_t)s * QS + d];
  }
  __syncthreads();
  // --- stage 2a: masked-score @ V ---
  const int e0 = sg * 16;
  float4 num[4] = {};
  for (int s = 0; s <= t; ++s) {
    const float av = At[s][t];
#pragma unroll
    for (int i = 0; i < 4; ++i) {
      const float4 v4 = *(const float4*)&KVP[s][e0 + 4 * i];
      num[i].x = fmaf(av, v4.x, num[i].x);
      num[i].y = fmaf(av, v4.y, num[i].y);
      num[i].z = fmaf(av, v4.z, num[i].z);
      num[i].w = fmaf(av, v4.w, num[i].w);
    }
  }
  __syncthreads();  // all V reads complete
  const float* Pg = S + (size_t)g * 4096;
  for (int l = tid; l < 4096; l += 256) KVP[l >> 6][l & 63] = Pg[l];
  __syncthreads();
  // --- stage 2b: Q @ P ---
  for (int d = 0; d < 64; ++d) {
    const float qd = Qt[d][t];
#pragma unroll
    for (int i = 0; i < 4; ++i) {
      const float4 p4 = *(const float4*)&KVP[d][e0 + 4 * i];
      num[i].x = fmaf(qd, p4.x, num[i].x);
      num[i].y = fmaf(qd, p4.y, num[i].y);
      num[i].z = fmaf(qd, p4.z, num[i].z);
      num[i].w = fmaf(qd, p4.w, num[i].w);
    }
  }
  const float inv = 1.f / den;
  float* yg = y + ybase + (size_t)t * (Hh * DHh) + e0;
#pragma unroll
  for (int i = 0; i < 4; ++i) {
    float4 o;
    o.x = num[i].x * inv;
    o.y = num[i].y * inv;
    o.z = num[i].z * inv;
    o.w = num[i].w * inv;
    *(float4*)&yg[4 * i] = o;
  }
}

// ---------------------------------------------------------------------------
// Per-head layernorm over DH=64, output bf16 [B,T,D].
// ---------------------------------------------------------------------------
__global__ __launch_bounds__(256) void ln_head(const float* __restrict__ y,
                                               const float* __restrict__ w,
                                               const float* __restrict__ bsh,
                                               __hip_bfloat16* __restrict__ out) {
  const int tid = threadIdx.x;
  const int e = tid & 63;
  const int r = blockIdx.x * 4 + (tid >> 6);
  const int h = r & (Hh - 1);
  const float val = y[(size_t)r * DHh + e];
  float s = val;
#pragma unroll
  for (int o = 1; o < 64; o <<= 1) s += __shfl_xor(s, o);
  const float mean = s * (1.f / 64.f);
  const float dv = val - mean;
  float s2 = dv * dv;
#pragma unroll
  for (int o = 1; o < 64; o <<= 1) s2 += __shfl_xor(s2, o);
  const float var = s2 * (1.f / 64.f);
  const float res = dv * rsqrtf(var + 1e-5f) * w[h * DHh + e] + bsh[h * DHh + e];
  out[(size_t)r * DHh + e] = __float2bfloat16(res);
}

// ---------------------------------------------------------------------------
// Fused FFN2-reduce + bias + relu + residual + final layernorm over D=1024.
// Reads the 2 split-K partials directly (saves the 16 MB f2 round trip).
// ---------------------------------------------------------------------------
__global__ __launch_bounds__(256) void final_ln(const float* __restrict__ x,
                                                const float* __restrict__ part,
                                                const float* __restrict__ b2,
                                                const float* __restrict__ w,
                                                const float* __restrict__ bb,
                                                float* __restrict__ out) {
  __shared__ float r1[4], r2[4];
  const int row = blockIdx.x;
  const int tid = threadIdx.x;
  const size_t off = (size_t)row * Dd + tid * 4;
  const size_t MN = (size_t)Mm * Dd;
  const float4 p0 = *(const float4*)&part[off];
  const float4 p1 = *(const float4*)&part[off + MN];
  const float4 bv = *(const float4*)&b2[tid * 4];
  const float4 xa = *(const float4*)&x[off];
  float z[4];
  z[0] = xa.x + fmaxf(p0.x + p1.x + bv.x, 0.f);
  z[1] = xa.y + fmaxf(p0.y + p1.y + bv.y, 0.f);
  z[2] = xa.z + fmaxf(p0.z + p1.z + bv.z, 0.f);
  z[3] = xa.w + fmaxf(p0.w + p1.w + bv.w, 0.f);
  float s1 = z[0] + z[1] + z[2] + z[3];
  float s2 = z[0] * z[0] + z[1] * z[1] + z[2] * z[2] + z[3] * z[3];
#pragma unroll
  for (int o = 1; o < 64; o <<= 1) {
    s1 += __shfl_xor(s1, o);
    s2 += __shfl_xor(s2, o);
  }
  const int wid = tid >> 6;
  if ((tid & 63) == 0) {
    r1[wid] = s1;
    r2[wid] = s2;
  }
  __syncthreads();
  const float t1 = r1[0] + r1[1] + r1[2] + r1[3];
  const float t2 = r2[0] + r2[1] + r2[2] + r2[3];
  const float mu = t1 * (1.f / Dd);
  const float var = t2 * (1.f / Dd) - mu * mu;
  const float rsv = rsqrtf(var + 1e-5f);
  float4 o4;
  float* op = &o4.x;
#pragma unroll
  for (int jj = 0; jj < 4; ++jj) op[jj] = (z[jj] - mu) * rsv * w[tid * 4 + jj] + bb[tid * 4 + jj];
  *(float4*)&out[off] = o4;
}

// ---------------------------------------------------------------------------
extern "C" void kernel_launch(void* const* d_in, const int* in_sizes, int n_in,
                              void* d_out, int out_size, void* d_ws, size_t ws_size,
                              hipStream_t stream) {
  const float* x = (const float*)d_in[0];
  const float* W_amp = (const float*)d_in[1];
  const float* b_amp = (const float*)d_in[2];
  const float* W_phi = (const float*)d_in[3];
  const float* b_phi = (const float*)d_in[4];
  const float* omega = (const float*)d_in[5];
  const float* ret_logit = (const float*)d_in[6];
  const float* theta = (const float*)d_in[7];
  const float* W_feat = (const float*)d_in[8];
  const float* b_feat = (const float*)d_in[9];
  const float* Wq = (const float*)d_in[10];
  const float* Wk = (const float*)d_in[11];
  const float* Wv = (const float*)d_in[12];
  const float* lnh_w = (const float*)d_in[13];
  const float* lnh_b = (const float*)d_in[14];
  const float* W1 = (const float*)d_in[15];
  const float* b1 = (const float*)d_in[16];
  const float* W2 = (const float*)d_in[17];
  const float* b2 = (const float*)d_in[18];
  const float* ln_w = (const float*)d_in[19];
  const float* ln_b = (const float*)d_in[20];

  // ---- workspace bump allocator (256B aligned) ----
  char* p = (char*)d_ws;
  auto alloc = [&](size_t bytes) {
    char* r = p;
    p += (bytes + 255) & ~(size_t)255;
    return r;
  };
  __hip_bfloat16* xb = (__hip_bfloat16*)alloc((size_t)Mm * Dd * 2);  // later: featb
  float* ur = (float*)alloc((size_t)Mm * NFf * 4);   // fp32 amp
  float* ui = (float*)alloc((size_t)Mm * NFf * 4);   // fp32 phi
  __hip_bfloat16* urh = (__hip_bfloat16*)alloc((size_t)Mm * NFf * 2);  // bf16 Re(u)
  __hip_bfloat16* uih = (__hip_bfloat16*)alloc((size_t)Mm * NFf * 2);  // bf16 Im(u)
  __hip_bfloat16* WTamp = (__hip_bfloat16*)alloc((size_t)NFf * Dd * 2);  // +WTphi contiguous
  __hip_bfloat16* WTphi = (__hip_bfloat16*)alloc((size_t)NFf * Dd * 2);
  __hip_bfloat16* WTfeat = (__hip_bfloat16*)alloc((size_t)Dd * 3 * NFf * 2);
  __hip_bfloat16* WTq = (__hip_bfloat16*)alloc((size_t)Dd * Dd * 2);  // +k+v contiguous
  __hip_bfloat16* WTk = (__hip_bfloat16*)alloc((size_t)Dd * Dd * 2);
  __hip_bfloat16* WTv = (__hip_bfloat16*)alloc((size_t)Dd * Dd * 2);
  __hip_bfloat16* WT1 = (__hip_bfloat16*)alloc((size_t)Rr * Dd * 2);
  __hip_bfloat16* WT2 = (__hip_bfloat16*)alloc((size_t)Dd * Rr * 2);
  __hip_bfloat16* hb = (__hip_bfloat16*)alloc((size_t)Mm * Dd * 2);
  float* qkv = (float*)alloc((size_t)Mm * QS * 4);  // 24 MB; later yhb + f1b
  float* y = (float*)alloc((size_t)Mm * Dd * 4);    // 8 MB; later partial[0]
  float* S = (float*)alloc((size_t)Bb * Hh * NCHK * 4096 * 4);  // 8 MB; later partial[1]
  float* Ksum = (float*)alloc((size_t)Bb * Hh * NCHK * 64 * 4);

  __hip_bfloat16* featb = xb;
  const float* q = qkv;
  const float* k = qkv + 1024;
  const float* v = qkv + 2048;
  __hip_bfloat16* yhb = (__hip_bfloat16*)qkv;                        // [M,1024] bf16 (4 MB)
  __hip_bfloat16* f1b = (__hip_bfloat16*)(qkv + (size_t)Mm * 1024);  // [M,4096] bf16 (16 MB)
  // FFN2 fp32 partials [2][M][1024] = 16 MB over y(8)+S(8): both dead after
  // ln_head / attn_out, and disjoint from f1b and WT2 (r4's overlay raced WT2).
  float* partial = y;
  float* out = (float*)d_out;

  const dim3 blk(256);

  // 0: casts
  cast_x<<<dim3(Mm * Dd / 1024), blk, 0, stream>>>(x, xb);
  TCDesc tc;
  tc.src[0] = W_amp; tc.dst[0] = WTamp;
  tc.src[1] = W_phi; tc.dst[1] = WTphi;
  tc.src[2] = W_feat; tc.dst[2] = WTfeat;
  tc.src[3] = Wq; tc.dst[3] = WTq;
  tc.src[4] = Wk; tc.dst[4] = WTk;
  tc.src[5] = Wv; tc.dst[5] = WTv;
  tc.src[6] = W1; tc.dst[6] = WT1;
  tc.src[7] = W2; tc.dst[7] = WT2;
  transpose_cast_all<<<dim3(12544), blk, 0, stream>>>(tc);

  // 1: fused amp/phi projection (N=512, dual epilogue -> ur, ui fp32)
  gemm_mfma<EPI_AMPPHI, 0, 0><<<dim3(512 / 128, Mm / 128), blk, 0, stream>>>(
      (const short*)xb, (const short*)WTamp, b_amp, b_phi, ur, ui, nullptr, Mm, 512, Dd);
  polar_kernel<<<dim3(Mm * NFf / 256), blk, 0, stream>>>(ur, ui, urh, uih);

  // 2: resonator scan -> feat (bf16); 16 blocks x 32 lanes
  resonator_scan<<<dim3(16), dim3(32), 0, stream>>>(urh, uih, omega, ret_logit, theta, featb);

  // 3: feat projection -> h (bf16)
  gemm_mfma<EPI_RELU, 1, 0><<<dim3(Dd / 128, Mm / 128), blk, 0, stream>>>(
      (const short*)featb, (const short*)WTfeat, b_feat, nullptr, nullptr, nullptr, hb, Mm, Dd, 3 * NFf);

  // 4: fused q,k,v projection (N=3072 -> qkv buffer, relu on q,k only)
  gemm_mfma<EPI_QKV, 0, 0><<<dim3(QS / 128, Mm / 128), blk, 0, stream>>>(
      (const short*)hb, (const short*)WTq, nullptr, nullptr, qkv, nullptr, nullptr, Mm, QS, Dd);

  // 5: chunked causal linear attention
  attn_chunk_kv<<<dim3(Bb * Hh * NCHK), blk, 0, stream>>>(k, v, S, Ksum);
  attn_prefix<<<dim3(Bb * Hh), blk, 0, stream>>>(S, Ksum);
  attn_out<<<dim3(Bb * Hh * NCHK), blk, 0, stream>>>(q, k, v, S, Ksum, y);

  // 6: per-head layernorm -> bf16 (qkv dead; yhb overlays it)
  ln_head<<<dim3(Bb * Tt * Hh / 4), blk, 0, stream>>>(y, lnh_w, lnh_b, yhb);

  // 7: FFN1 -> f1b (bf16)
  gemm_mfma<EPI_RELU, 1, 0><<<dim3(Rr / 128, Mm / 128), blk, 0, stream>>>(
      (const short*)yhb, (const short*)WT1, b1, nullptr, nullptr, nullptr, f1b, Mm, Rr, Dd);

  // 8: FFN2 split-K=2 -> partials over y+S (grid = 256 blocks = full machine)
  gemm_mfma<EPI_NONE, 0, 2><<<dim3(Dd / 128, Mm / 128, 2), blk, 0, stream>>>(
      (const short*)f1b, (const short*)WT2, nullptr, nullptr, partial, nullptr, nullptr, Mm, Dd, Rr);

  // 9: fused reduce + bias + relu + residual + final layernorm
  final_ln<<<dim3(Mm), blk, 0, stream>>>(x, partial, b2, ln_w, ln_b, out);
}

// Round 7
// 294.597 us; speedup vs baseline: 1.2380x; 1.2380x over previous
//
#include <hip/hip_runtime.h>
#include <hip/hip_bf16.h>
#include <math.h>

#ifndef M_PI_F
#define M_PI_F 3.14159265358979323846f
#endif

static constexpr int Bb = 2, Tt = 1024, Dd = 1024, Hh = 16, DHh = 64, NFf = 256, Rr = 4096;
static constexpr int Mm = Bb * Tt;
static constexpr int CHK = 64, NCHK = Tt / CHK;  // attention chunking
static constexpr int QS = 3072;                  // fused qkv row stride

enum Epi { EPI_NONE = 0, EPI_RELU, EPI_QKV, EPI_AMPPHI };

typedef __attribute__((ext_vector_type(8))) short bf16x8;
typedef __attribute__((ext_vector_type(4))) float f32x4;

// ---------------------------------------------------------------------------
// async global->LDS, 16B per lane. LDS dest is wave-uniform base; HW adds
// lane*16. Global address is per-lane.
// ---------------------------------------------------------------------------
__device__ inline void gload16(const short* g, short* l) {
  __builtin_amdgcn_global_load_lds(
      (const __attribute__((address_space(1))) unsigned int*)g,
      (__attribute__((address_space(3))) unsigned int*)l, 16, 0, 0);
}

// ---------------------------------------------------------------------------
// bf16 MFMA GEMM: C[M,N] = epi(A[M,K] @ BT[N,K]^T + bias)
// 128x128 tile, BK=64, 4 waves (2x2), each 64x64 via 4x4 frags of 16x16x32.
// - LDS XOR bank-swizzle (rule #21 both-sides involution): gload_lds dest
//   linear, global SOURCE pre-permuted (skk), ds_read applies same XOR.
// - Bijective XCD swizzle (m204) for A-panel L2 reuse per XCD.
// - SPLITK (=#slices): blockIdx.z selects K-slice, writes fp32 partial at
//   Cf + z*M*N (no epilogue). Partial buffer placement is the CALLER's
//   responsibility — must not overlap A or BT (r4 had such a race).
// ---------------------------------------------------------------------------
template <int EPI, int OUTBF, int SPLITK>
__global__ __launch_bounds__(256) void gemm_mfma(const short* __restrict__ A,
                                                 const short* __restrict__ BT,
                                                 const float* __restrict__ bias,
                                                 const float* __restrict__ bias2,
                                                 float* __restrict__ Cf,
                                                 float* __restrict__ Cf2,
                                                 __hip_bfloat16* __restrict__ Cb,
                                                 int M, int N, int ldk) {
  __shared__ short lA[128 * 64];
  __shared__ short lB[128 * 64];
  const int tid = threadIdx.x;
  const int wid = tid >> 6, lane = tid & 63;

  // XCD-aware bijective block swizzle (grids here always have nwg % 8 == 0)
  const int nwg = gridDim.x * gridDim.y;
  const int wg = blockIdx.y * gridDim.x + blockIdx.x;
  const int qq = nwg >> 3, rr = nwg & 7;
  const int xcd = wg & 7, idx = wg >> 3;
  const int wg2 = (xcd < rr ? xcd * (qq + 1) : rr * (qq + 1) + (xcd - rr) * qq) + idx;
  const int bx = wg2 % gridDim.x, by = wg2 / gridDim.x;

  const int m0 = by * 128, n0 = bx * 128;
  const int wm = (wid >> 1) * 64, wn = (wid & 1) * 64;
  const int srow = lane >> 3;                            // row within 8-row slab
  const int skk = (((lane & 7) ^ (lane >> 3)) << 3);     // swizzled k offset (elems)

  int kstart = 0, klen = ldk;
  if (SPLITK > 1) {
    klen = ldk / SPLITK;
    kstart = blockIdx.z * klen;
    Cf += (size_t)blockIdx.z * M * N;
  }

  f32x4 acc[4][4] = {};

  for (int k0 = kstart; k0 < kstart + klen; k0 += 64) {
#pragma unroll
    for (int si = 0; si < 4; ++si) {
      const int s = wid + si * 4;  // stage instruction index 0..15
      gload16(A + (size_t)(m0 + s * 8 + srow) * ldk + k0 + skk, &lA[s * 512]);
      gload16(BT + (size_t)(n0 + s * 8 + srow) * ldk + k0 + skk, &lB[s * 512]);
    }
    __syncthreads();  // drains vmcnt -> LDS tiles ready
#pragma unroll
    for (int kk = 0; kk < 2; ++kk) {
      const int krd = kk * 32 + (lane >> 4) * 8;
      const int rsel = lane & 15;
      const int kswz = krd ^ ((rsel & 7) << 3);  // same involution as store side
      bf16x8 af[4], bfr[4];
#pragma unroll
      for (int i = 0; i < 4; ++i) {
        af[i] = *(const bf16x8*)&lA[(wm + i * 16 + rsel) * 64 + kswz];
        bfr[i] = *(const bf16x8*)&lB[(wn + i * 16 + rsel) * 64 + kswz];
      }
#pragma unroll
      for (int i = 0; i < 4; ++i)
#pragma unroll
        for (int j = 0; j < 4; ++j)
          acc[i][j] = __builtin_amdgcn_mfma_f32_16x16x32_bf16(af[i], bfr[j], acc[i][j], 0, 0, 0);
    }
    __syncthreads();  // compute done before restage
  }

  const int crow = (lane >> 4) * 4;
  const int ccol = lane & 15;
#pragma unroll
  for (int j = 0; j < 4; ++j) {
    const int col = n0 + wn + j * 16 + ccol;
    float bv = 0.f;
    if (EPI == EPI_AMPPHI) {
      bv = (col < NFf) ? bias[col] : bias2[col - NFf];
    } else if (bias) {
      bv = bias[col];
    }
#pragma unroll
    for (int i = 0; i < 4; ++i) {
#pragma unroll
      for (int r = 0; r < 4; ++r) {
        float v = acc[i][j][r] + bv;
        const int row = m0 + wm + i * 16 + crow + r;
        if (EPI == EPI_AMPPHI) {
          if (col < NFf) {
            v = (v > 0.f) ? (v + log1pf(expf(-v))) : log1pf(expf(v));  // softplus
            Cf[(size_t)row * NFf + col] = v;
          } else {
            Cf2[(size_t)row * NFf + (col - NFf)] = M_PI_F * tanhf(v);
          }
        } else if (EPI == EPI_QKV) {
          Cf[(size_t)row * QS + col] = (col < 2048) ? fmaxf(v, 0.f) : v;
        } else {
          if (EPI == EPI_RELU) v = fmaxf(v, 0.f);
          const size_t off = (size_t)row * N + col;
          if (OUTBF)
            Cb[off] = __float2bfloat16(v);
          else
            Cf[off] = v;
        }
      }
    }
  }
}

// ---------------------------------------------------------------------------
// Fused transpose-cast of all 8 weight matrices: W[K,N] f32 -> WT[N,K] bf16.
// ---------------------------------------------------------------------------
struct TCDesc {
  const float* src[8];
  __hip_bfloat16* dst[8];
};

__global__ __launch_bounds__(256) void transpose_cast_all(TCDesc d) {
  constexpr int KS[8] = {1024, 1024, 768, 1024, 1024, 1024, 1024, 4096};
  constexpr int NS[8] = {256, 256, 1024, 1024, 1024, 1024, 4096, 1024};
  constexpr int CUM[9] = {0, 256, 512, 1280, 2304, 3328, 4352, 8448, 12544};
  __shared__ float tile[32][33];
  const int bid = blockIdx.x;
  int w = 0;
#pragma unroll
  for (int i = 0; i < 8; ++i)
    if (bid >= CUM[i + 1]) w = i + 1;
  const int tlocal = bid - CUM[w];
  const int K = KS[w], N = NS[w];
  const int tilesN = N / 32;
  const int bk = (tlocal / tilesN) * 32, bn = (tlocal % tilesN) * 32;
  const float* W = d.src[w];
  __hip_bfloat16* WT = d.dst[w];
  const int tx = threadIdx.x & 31, ty = threadIdx.x >> 5;  // 32x8
#pragma unroll
  for (int r = 0; r < 32; r += 8) tile[ty + r][tx] = W[(size_t)(bk + ty + r) * N + bn + tx];
  __syncthreads();
#pragma unroll
  for (int r = 0; r < 32; r += 8)
    WT[(size_t)(bn + ty + r) * K + bk + tx] = __float2bfloat16(tile[tx][ty + r]);
}

// ---------------------------------------------------------------------------
// x: f32 -> bf16 cast (row-major, layout preserved)
// ---------------------------------------------------------------------------
__global__ __launch_bounds__(256) void cast_x(const float* __restrict__ x,
                                              __hip_bfloat16* __restrict__ xb) {
  const int i = (blockIdx.x * 256 + threadIdx.x) * 4;
  const float4 v = *(const float4*)&x[i];
  xb[i + 0] = __float2bfloat16(v.x);
  xb[i + 1] = __float2bfloat16(v.y);
  xb[i + 2] = __float2bfloat16(v.z);
  xb[i + 3] = __float2bfloat16(v.w);
}

// ---------------------------------------------------------------------------
// polar -> cartesian, fp32 (amp,phi) -> bf16 (amp*cos, amp*sin).
// ---------------------------------------------------------------------------
__global__ __launch_bounds__(256) void polar_kernel(const float* __restrict__ a,
                                                    const float* __restrict__ p,
                                                    __hip_bfloat16* __restrict__ outr,
                                                    __hip_bfloat16* __restrict__ outi) {
  const int i = blockIdx.x * 256 + threadIdx.x;
  const float am = a[i], ph = p[i];
  float s, c;
  sincosf(ph, &s, &c);
  outr[i] = __float2bfloat16(am * c);
  outi[i] = __float2bfloat16(am * s);
}

// ---------------------------------------------------------------------------
// Sequential complex resonator recurrence; writes feat bf16 [B,T,3*NF].
// TIME-CHUNK PARALLEL (r6 post-mortem): the gated recurrence contracts by
// >= sigmoid(ret_logit)=0.881/step (gate g<1 shrinks it further), so a
// 128-step warm-up from X=0 reconstructs state to ~1e-7 rel worst-case,
// ~1e-12 typical — below feat's bf16 quantization. 8 time chunks x 4 freq
// slices x B = 64 blocks x 64 lanes (wide 128B requests — r6's 32-lane
// blocks quartered per-request bytes and regressed). Register double-buffer
// (P=16) keeps ~4KB/wave in flight.
// ---------------------------------------------------------------------------
static constexpr int RES_P = 16;
static constexpr int RES_TC = 128;  // chunk length
static constexpr int RES_W = 128;   // warm-up length

#define RES_LOAD(buf_r, buf_i, tg)                                        \
  if ((tg) < cend) {                                                      \
    _Pragma("unroll") for (int i = 0; i < RES_P; ++i) {                   \
      buf_r[i] = __bfloat162float(ur[bbase + (size_t)((tg) + i) * NFf]);  \
      buf_i[i] = __bfloat162float(ui[bbase + (size_t)((tg) + i) * NFf]);  \
    }                                                                     \
  }

#define RES_STEP(buf_r, buf_i, tg)                                     \
  {                                                                     \
    const bool wr_ = (tg) >= cstart;                                    \
    _Pragma("unroll") for (int i = 0; i < RES_P; ++i) {                 \
      const float pr = fmaf(ar, Xr, fmaf(-ai, Xi, buf_r[i]));           \
      const float pim = fmaf(ar, Xi, fmaf(ai, Xr, buf_i[i]));           \
      const float mag = __builtin_amdgcn_sqrtf(fmaf(pr, pr, pim * pim)); \
      const float g = __builtin_amdgcn_rcpf(1.f + __expf(th - mag));    \
      Xr = pr * g;                                                      \
      Xi = pim * g;                                                     \
      if (wr_) {                                                        \
        const size_t fb = ((size_t)b * Tt + (tg) + i) * (3 * NFf);      \
        featb[fb + f] = __float2bfloat16(Xr);                           \
        featb[fb + NFf + f] = __float2bfloat16(Xi);                     \
        featb[fb + 2 * NFf + f] = __float2bfloat16(mag * g);            \
      }                                                                 \
    }                                                                   \
  }

__global__ __launch_bounds__(64) void resonator_scan(const __hip_bfloat16* __restrict__ ur,
                                                     const __hip_bfloat16* __restrict__ ui,
                                                     const float* __restrict__ omega,
                                                     const float* __restrict__ ret_logit,
                                                     const float* __restrict__ theta,
                                                     __hip_bfloat16* __restrict__ featb) {
  const int bid = blockIdx.x;            // 64 blocks: (b:2, fs:4, tc:8)
  const int tc = bid & 7;
  const int fs = (bid >> 3) & 3;
  const int b = bid >> 5;
  const int f = fs * 64 + threadIdx.x;
  const int cstart = tc * RES_TC;
  const int cend = cstart + RES_TC;
  const int tbeg = (cstart >= RES_W) ? cstart - RES_W : 0;

  const float dec = 1.f / (1.f + __expf(-ret_logit[f]));
  float so, co;
  sincosf(omega[f], &so, &co);
  const float ar = dec * co, ai = dec * so;
  const float th = theta[f];
  const size_t bbase = (size_t)b * Tt * NFf + f;
  float Xr = 0.f, Xi = 0.f;
  float Ar[RES_P], Ai[RES_P], Br[RES_P], Bi[RES_P];
  RES_LOAD(Ar, Ai, tbeg);
  for (int t0 = tbeg; t0 < cend; t0 += 2 * RES_P) {
    RES_LOAD(Br, Bi, t0 + RES_P);
    RES_STEP(Ar, Ai, t0);
    RES_LOAD(Ar, Ai, t0 + 2 * RES_P);
    RES_STEP(Br, Bi, t0 + RES_P);
  }
}

// ---------------------------------------------------------------------------
// Attention phase A: per-chunk KV outer-product sums and k-sums.
// q/k/v live in the fused qkv buffer (row stride QS=3072).
// ---------------------------------------------------------------------------
__global__ __launch_bounds__(256) void attn_chunk_kv(const float* __restrict__ k,
                                                     const float* __restrict__ v,
                                                     float* __restrict__ S,
                                                     float* __restrict__ Ksum) {
  __shared__ float Ks[64][68], Vs[64][68];
  const int g = blockIdx.x;
  const int j = g & (NCHK - 1), bh = g >> 4;
  const int b = bh >> 4, h = bh & (Hh - 1);
  const int tid = threadIdx.x;
  const size_t rowbase = (size_t)(b * Tt + j * CHK) * QS + h * DHh;
  for (int l = tid; l < 4096; l += 256) {
    const int s = l >> 6, d = l & 63;
    Ks[s][d] = k[rowbase + (size_t)s * QS + d];
    Vs[s][d] = v[rowbase + (size_t)s * QS + d];
  }
  __syncthreads();
  const int d0 = tid & 63, eb = tid >> 6, e0 = eb * 16;
  float4 acc4[4] = {};
  float ks = 0.f;
  for (int s = 0; s < 64; ++s) {
    const float kd = Ks[s][d0];
    ks += kd;
#pragma unroll
    for (int i = 0; i < 4; ++i) {
      const float4 v4 = *(const float4*)&Vs[s][e0 + 4 * i];
      acc4[i].x = fmaf(kd, v4.x, acc4[i].x);
      acc4[i].y = fmaf(kd, v4.y, acc4[i].y);
      acc4[i].z = fmaf(kd, v4.z, acc4[i].z);
      acc4[i].w = fmaf(kd, v4.w, acc4[i].w);
    }
  }
  float* Sg = S + (size_t)g * 4096 + (size_t)d0 * 64 + e0;
#pragma unroll
  for (int i = 0; i < 4; ++i) *(float4*)&Sg[4 * i] = acc4[i];
  if (eb == 0) Ksum[(size_t)g * 64 + d0] = ks;
}

// ---------------------------------------------------------------------------
// Attention phase B: in-place EXCLUSIVE prefix over the 16 chunks per (b,h).
// ---------------------------------------------------------------------------
__global__ __launch_bounds__(256) void attn_prefix(float* __restrict__ S,
                                                   float* __restrict__ Ksum) {
  const int bh = blockIdx.x;
  const int tid = threadIdx.x;
  for (int r = 0; r < 16; ++r) {
    const int de = r * 256 + tid;
    float run = 0.f;
    size_t p = (size_t)bh * (NCHK * 4096) + de;
    for (int j = 0; j < NCHK; ++j, p += 4096) {
      const float tmp = S[p];
      S[p] = run;
      run += tmp;
    }
  }
  if (tid < 64) {
    float run = 0.f;
    size_t p = (size_t)bh * (NCHK * 64) + tid;
    for (int j = 0; j < NCHK; ++j, p += 64) {
      const float tmp = Ksum[p];
      Ksum[p] = run;
      run += tmp;
    }
  }
}

// ---------------------------------------------------------------------------
// Attention phase C: per-chunk output (q/k/v strided QS; y is [B,T,H,DH]).
// ---------------------------------------------------------------------------
__global__ __launch_bounds__(256) void attn_out(const float* __restrict__ q,
                                                const float* __restrict__ k,
                                                const float* __restrict__ v,
                                                const float* __restrict__ S,
                                                const float* __restrict__ Ksum,
                                                float* __restrict__ y) {
  __shared__ float Qt[64][65];
  __shared__ float KVP[64][68];
  __shared__ float At[64][65];
  const int g = blockIdx.x;
  const int j = g & (NCHK - 1), bh = g >> 4;
  const int b = bh >> 4, h = bh & (Hh - 1);
  const int tid = threadIdx.x;
  const size_t rowbase = (size_t)(b * Tt + j * CHK) * QS + h * DHh;
  const size_t ybase = (((size_t)b * Tt + j * CHK) * Hh + h) * DHh;
  for (int l = tid; l < 4096; l += 256) {
    const int s = l >> 6, d = l & 63;
    Qt[d][s] = q[rowbase + (size_t)s * QS + d];
    KVP[s][d] = k[rowbase + (size_t)s * QS + d];
  }
  __syncthreads();
  const int t = tid >> 2, sg = tid & 3;
  const float* pk = Ksum + (size_t)g * 64;
  // --- stage 1: masked scores + denominator ---
  float adot[16] = {};
  float qpk = 0.f;
  for (int c = 0; c < 16; ++c) {
    const float q0 = Qt[4 * c + 0][t], q1 = Qt[4 * c + 1][t];
    const float q2 = Qt[4 * c + 2][t], q3 = Qt[4 * c + 3][t];
    const float4 pk4 = *(const float4*)&pk[4 * c];
    qpk = fmaf(q0, pk4.x, fmaf(q1, pk4.y, fmaf(q2, pk4.z, fmaf(q3, pk4.w, qpk))));
#pragma unroll
    for (int i = 0; i < 16; ++i) {
      const float4 k4 = *(const float4*)&KVP[sg * 16 + i][4 * c];
      adot[i] = fmaf(q0, k4.x, fmaf(q1, k4.y, fmaf(q2, k4.z, fmaf(q3, k4.w, adot[i]))));
    }
  }
  float rs = 0.f;
#pragma unroll
  for (int i = 0; i < 16; ++i) {
    if (sg * 16 + i > t) adot[i] = 0.f;
    rs += adot[i];
  }
  rs += __shfl_xor(rs, 1);
  rs += __shfl_xor(rs, 2);
  const float den = qpk + rs + 1e-6f;
  __syncthreads();  // all K reads complete
#pragma unroll
  for (int i = 0; i < 16; ++i) At[sg * 16 + i][t] = adot[i];
  for (int l = tid; l < 4096; l += 256) {  // overwrite K with V
    const int s = l >> 6, d = l & 63;
    KVP[s][d] = v[rowbase + (size_t)s * QS + d];
  }
  __syncthreads();
  // --- stage 2a: masked-score @ V ---
  const int e0 = sg * 16;
  float4 num[4] = {};
  for (int s = 0; s <= t; ++s) {
    const float av = At[s][t];
#pragma unroll
    for (int i = 0; i < 4; ++i) {
      const float4 v4 = *(const float4*)&KVP[s][e0 + 4 * i];
      num[i].x = fmaf(av, v4.x, num[i].x);
      num[i].y = fmaf(av, v4.y, num[i].y);
      num[i].z = fmaf(av, v4.z, num[i].z);
      num[i].w = fmaf(av, v4.w, num[i].w);
    }
  }
  __syncthreads();  // all V reads complete
  const float* Pg = S + (size_t)g * 4096;
  for (int l = tid; l < 4096; l += 256) KVP[l >> 6][l & 63] = Pg[l];
  __syncthreads();
  // --- stage 2b: Q @ P ---
  for (int d = 0; d < 64; ++d) {
    const float qd = Qt[d][t];
#pragma unroll
    for (int i = 0; i < 4; ++i) {
      const float4 p4 = *(const float4*)&KVP[d][e0 + 4 * i];
      num[i].x = fmaf(qd, p4.x, num[i].x);
      num[i].y = fmaf(qd, p4.y, num[i].y);
      num[i].z = fmaf(qd, p4.z, num[i].z);
      num[i].w = fmaf(qd, p4.w, num[i].w);
    }
  }
  const float inv = 1.f / den;
  float* yg = y + ybase + (size_t)t * (Hh * DHh) + e0;
#pragma unroll
  for (int i = 0; i < 4; ++i) {
    float4 o;
    o.x = num[i].x * inv;
    o.y = num[i].y * inv;
    o.z = num[i].z * inv;
    o.w = num[i].w * inv;
    *(float4*)&yg[4 * i] = o;
  }
}

// ---------------------------------------------------------------------------
// Per-head layernorm over DH=64, output bf16 [B,T,D].
// ---------------------------------------------------------------------------
__global__ __launch_bounds__(256) void ln_head(const float* __restrict__ y,
                                               const float* __restrict__ w,
                                               const float* __restrict__ bsh,
                                               __hip_bfloat16* __restrict__ out) {
  const int tid = threadIdx.x;
  const int e = tid & 63;
  const int r = blockIdx.x * 4 + (tid >> 6);
  const int h = r & (Hh - 1);
  const float val = y[(size_t)r * DHh + e];
  float s = val;
#pragma unroll
  for (int o = 1; o < 64; o <<= 1) s += __shfl_xor(s, o);
  const float mean = s * (1.f / 64.f);
  const float dv = val - mean;
  float s2 = dv * dv;
#pragma unroll
  for (int o = 1; o < 64; o <<= 1) s2 += __shfl_xor(s2, o);
  const float var = s2 * (1.f / 64.f);
  const float res = dv * rsqrtf(var + 1e-5f) * w[h * DHh + e] + bsh[h * DHh + e];
  out[(size_t)r * DHh + e] = __float2bfloat16(res);
}

// ---------------------------------------------------------------------------
// Fused FFN2-reduce + bias + relu + residual + final layernorm over D=1024.
// ---------------------------------------------------------------------------
__global__ __launch_bounds__(256) void final_ln(const float* __restrict__ x,
                                                const float* __restrict__ part,
                                                const float* __restrict__ b2,
                                                const float* __restrict__ w,
                                                const float* __restrict__ bb,
                                                float* __restrict__ out) {
  __shared__ float r1[4], r2[4];
  const int row = blockIdx.x;
  const int tid = threadIdx.x;
  const size_t off = (size_t)row * Dd + tid * 4;
  const size_t MN = (size_t)Mm * Dd;
  const float4 p0 = *(const float4*)&part[off];
  const float4 p1 = *(const float4*)&part[off + MN];
  const float4 bv = *(const float4*)&b2[tid * 4];
  const float4 xa = *(const float4*)&x[off];
  float z[4];
  z[0] = xa.x + fmaxf(p0.x + p1.x + bv.x, 0.f);
  z[1] = xa.y + fmaxf(p0.y + p1.y + bv.y, 0.f);
  z[2] = xa.z + fmaxf(p0.z + p1.z + bv.z, 0.f);
  z[3] = xa.w + fmaxf(p0.w + p1.w + bv.w, 0.f);
  float s1 = z[0] + z[1] + z[2] + z[3];
  float s2 = z[0] * z[0] + z[1] * z[1] + z[2] * z[2] + z[3] * z[3];
#pragma unroll
  for (int o = 1; o < 64; o <<= 1) {
    s1 += __shfl_xor(s1, o);
    s2 += __shfl_xor(s2, o);
  }
  const int wid = tid >> 6;
  if ((tid & 63) == 0) {
    r1[wid] = s1;
    r2[wid] = s2;
  }
  __syncthreads();
  const float t1 = r1[0] + r1[1] + r1[2] + r1[3];
  const float t2 = r2[0] + r2[1] + r2[2] + r2[3];
  const float mu = t1 * (1.f / Dd);
  const float var = t2 * (1.f / Dd) - mu * mu;
  const float rsv = rsqrtf(var + 1e-5f);
  float4 o4;
  float* op = &o4.x;
#pragma unroll
  for (int jj = 0; jj < 4; ++jj) op[jj] = (z[jj] - mu) * rsv * w[tid * 4 + jj] + bb[tid * 4 + jj];
  *(float4*)&out[off] = o4;
}

// ---------------------------------------------------------------------------
extern "C" void kernel_launch(void* const* d_in, const int* in_sizes, int n_in,
                              void* d_out, int out_size, void* d_ws, size_t ws_size,
                              hipStream_t stream) {
  const float* x = (const float*)d_in[0];
  const float* W_amp = (const float*)d_in[1];
  const float* b_amp = (const float*)d_in[2];
  const float* W_phi = (const float*)d_in[3];
  const float* b_phi = (const float*)d_in[4];
  const float* omega = (const float*)d_in[5];
  const float* ret_logit = (const float*)d_in[6];
  const float* theta = (const float*)d_in[7];
  const float* W_feat = (const float*)d_in[8];
  const float* b_feat = (const float*)d_in[9];
  const float* Wq = (const float*)d_in[10];
  const float* Wk = (const float*)d_in[11];
  const float* Wv = (const float*)d_in[12];
  const float* lnh_w = (const float*)d_in[13];
  const float* lnh_b = (const float*)d_in[14];
  const float* W1 = (const float*)d_in[15];
  const float* b1 = (const float*)d_in[16];
  const float* W2 = (const float*)d_in[17];
  const float* b2 = (const float*)d_in[18];
  const float* ln_w = (const float*)d_in[19];
  const float* ln_b = (const float*)d_in[20];

  // ---- workspace bump allocator (256B aligned) ----
  char* p = (char*)d_ws;
  auto alloc = [&](size_t bytes) {
    char* r = p;
    p += (bytes + 255) & ~(size_t)255;
    return r;
  };
  __hip_bfloat16* xb = (__hip_bfloat16*)alloc((size_t)Mm * Dd * 2);  // later: featb
  float* ur = (float*)alloc((size_t)Mm * NFf * 4);   // fp32 amp
  float* ui = (float*)alloc((size_t)Mm * NFf * 4);   // fp32 phi
  __hip_bfloat16* urh = (__hip_bfloat16*)alloc((size_t)Mm * NFf * 2);  // bf16 Re(u)
  __hip_bfloat16* uih = (__hip_bfloat16*)alloc((size_t)Mm * NFf * 2);  // bf16 Im(u)
  __hip_bfloat16* WTamp = (__hip_bfloat16*)alloc((size_t)NFf * Dd * 2);  // +WTphi contiguous
  __hip_bfloat16* WTphi = (__hip_bfloat16*)alloc((size_t)NFf * Dd * 2);
  __hip_bfloat16* WTfeat = (__hip_bfloat16*)alloc((size_t)Dd * 3 * NFf * 2);
  __hip_bfloat16* WTq = (__hip_bfloat16*)alloc((size_t)Dd * Dd * 2);  // +k+v contiguous
  __hip_bfloat16* WTk = (__hip_bfloat16*)alloc((size_t)Dd * Dd * 2);
  __hip_bfloat16* WTv = (__hip_bfloat16*)alloc((size_t)Dd * Dd * 2);
  __hip_bfloat16* WT1 = (__hip_bfloat16*)alloc((size_t)Rr * Dd * 2);
  __hip_bfloat16* WT2 = (__hip_bfloat16*)alloc((size_t)Dd * Rr * 2);
  __hip_bfloat16* hb = (__hip_bfloat16*)alloc((size_t)Mm * Dd * 2);
  float* qkv = (float*)alloc((size_t)Mm * QS * 4);  // 24 MB; later yhb + f1b
  float* y = (float*)alloc((size_t)Mm * Dd * 4);    // 8 MB; later partial[0]
  float* S = (float*)alloc((size_t)Bb * Hh * NCHK * 4096 * 4);  // 8 MB; later partial[1]
  float* Ksum = (float*)alloc((size_t)Bb * Hh * NCHK * 64 * 4);

  __hip_bfloat16* featb = xb;
  const float* q = qkv;
  const float* k = qkv + 1024;
  const float* v = qkv + 2048;
  __hip_bfloat16* yhb = (__hip_bfloat16*)qkv;                        // [M,1024] bf16 (4 MB)
  __hip_bfloat16* f1b = (__hip_bfloat16*)(qkv + (size_t)Mm * 1024);  // [M,4096] bf16 (16 MB)
  // FFN2 fp32 partials [2][M][1024] = 16 MB over y(8)+S(8): both dead after
  // ln_head / attn_out, and disjoint from f1b and WT2 (r4's overlay raced WT2).
  float* partial = y;
  float* out = (float*)d_out;

  const dim3 blk(256);

  // 0: casts
  cast_x<<<dim3(Mm * Dd / 1024), blk, 0, stream>>>(x, xb);
  TCDesc tc;
  tc.src[0] = W_amp; tc.dst[0] = WTamp;
  tc.src[1] = W_phi; tc.dst[1] = WTphi;
  tc.src[2] = W_feat; tc.dst[2] = WTfeat;
  tc.src[3] = Wq; tc.dst[3] = WTq;
  tc.src[4] = Wk; tc.dst[4] = WTk;
  tc.src[5] = Wv; tc.dst[5] = WTv;
  tc.src[6] = W1; tc.dst[6] = WT1;
  tc.src[7] = W2; tc.dst[7] = WT2;
  transpose_cast_all<<<dim3(12544), blk, 0, stream>>>(tc);

  // 1: fused amp/phi projection (N=512, dual epilogue -> ur, ui fp32)
  gemm_mfma<EPI_AMPPHI, 0, 0><<<dim3(512 / 128, Mm / 128), blk, 0, stream>>>(
      (const short*)xb, (const short*)WTamp, b_amp, b_phi, ur, ui, nullptr, Mm, 512, Dd);
  polar_kernel<<<dim3(Mm * NFf / 256), blk, 0, stream>>>(ur, ui, urh, uih);

  // 2: resonator scan -> feat (bf16); 64 blocks x 64 lanes, time-chunked
  resonator_scan<<<dim3(64), dim3(64), 0, stream>>>(urh, uih, omega, ret_logit, theta, featb);

  // 3: feat projection -> h (bf16)
  gemm_mfma<EPI_RELU, 1, 0><<<dim3(Dd / 128, Mm / 128), blk, 0, stream>>>(
      (const short*)featb, (const short*)WTfeat, b_feat, nullptr, nullptr, nullptr, hb, Mm, Dd, 3 * NFf);

  // 4: fused q,k,v projection (N=3072 -> qkv buffer, relu on q,k only)
  gemm_mfma<EPI_QKV, 0, 0><<<dim3(QS / 128, Mm / 128), blk, 0, stream>>>(
      (const short*)hb, (const short*)WTq, nullptr, nullptr, qkv, nullptr, nullptr, Mm, QS, Dd);

  // 5: chunked causal linear attention
  attn_chunk_kv<<<dim3(Bb * Hh * NCHK), blk, 0, stream>>>(k, v, S, Ksum);
  attn_prefix<<<dim3(Bb * Hh), blk, 0, stream>>>(S, Ksum);
  attn_out<<<dim3(Bb * Hh * NCHK), blk, 0, stream>>>(q, k, v, S, Ksum, y);

  // 6: per-head layernorm -> bf16 (qkv dead; yhb overlays it)
  ln_head<<<dim3(Bb * Tt * Hh / 4), blk, 0, stream>>>(y, lnh_w, lnh_b, yhb);

  // 7: FFN1 -> f1b (bf16)
  gemm_mfma<EPI_RELU, 1, 0><<<dim3(Rr / 128, Mm / 128), blk, 0, stream>>>(
      (const short*)yhb, (const short*)WT1, b1, nullptr, nullptr, nullptr, f1b, Mm, Rr, Dd);

  // 8: FFN2 split-K=2 -> partials over y+S (grid = 256 blocks = full machine)
  gemm_mfma<EPI_NONE, 0, 2><<<dim3(Dd / 128, Mm / 128, 2), blk, 0, stream>>>(
      (const short*)f1b, (const short*)WT2, nullptr, nullptr, partial, nullptr, nullptr, Mm, Dd, Rr);

  // 9: fused reduce + bias + relu + residual + final layernorm
  final_ln<<<dim3(Mm), blk, 0, stream>>>(x, partial, b2, ln_w, ln_b, out);
}

// Round 8
// 233.712 us; speedup vs baseline: 1.5605x; 1.2605x over previous
//
#include <hip/hip_runtime.h>
#include <hip/hip_bf16.h>
#include <math.h>

#ifndef M_PI_F
#define M_PI_F 3.14159265358979323846f
#endif

static constexpr int Bb = 2, Tt = 1024, Dd = 1024, Hh = 16, DHh = 64, NFf = 256, Rr = 4096;
static constexpr int Mm = Bb * Tt;
static constexpr int CHK = 64, NCHK = Tt / CHK;  // attention chunking
static constexpr int QS = 3072;                  // fused qkv row stride

enum Epi { EPI_NONE = 0, EPI_RELU, EPI_QKV };

typedef __attribute__((ext_vector_type(8))) short bf16x8;
typedef __attribute__((ext_vector_type(4))) float f32x4;

// ---------------------------------------------------------------------------
// async global->LDS, 16B per lane. LDS dest is wave-uniform base; HW adds
// lane*16. Global address is per-lane.
// ---------------------------------------------------------------------------
__device__ inline void gload16(const short* g, short* l) {
  __builtin_amdgcn_global_load_lds(
      (const __attribute__((address_space(1))) unsigned int*)g,
      (__attribute__((address_space(3))) unsigned int*)l, 16, 0, 0);
}

// ---------------------------------------------------------------------------
// bf16 MFMA GEMM: C[M,N] = epi(A[M,K] @ BT[N,K]^T + bias)
// 128x128 tile, BK=64, 4 waves (2x2), each 64x64 via 4x4 frags of 16x16x32.
// - DOUBLE-BUFFERED K-loop (T3 minimum-2-phase, r7): stage next tile, counted
//   s_waitcnt vmcnt(8) (NOT vmcnt(0) — __syncthreads would drain the just-
//   issued prefetch), raw s_barrier, compute current, s_barrier. At 1 block/CU
//   (small grids) there is no implicit wave overlap, so this is the only
//   mechanism hiding load latency.
// - LDS XOR bank-swizzle (rule #21 both-sides involution).
// - Bijective XCD swizzle (m204) for A-panel L2 reuse per XCD.
// - SPLITK: blockIdx.z selects K-slice, writes fp32 partial at Cf + z*M*N.
//   Caller must place partials disjoint from A and BT (r4 had such a race).
// ---------------------------------------------------------------------------
#define GSTAGE(bufsel, kk0)                                                          \
  _Pragma("unroll") for (int si = 0; si < 4; ++si) {                                 \
    const int s = wid + si * 4;                                                      \
    gload16(A + (size_t)(m0 + s * 8 + srow) * ldk + (kk0) + skk,                     \
            &lA[(bufsel) * 8192 + s * 512]);                                         \
    gload16(BT + (size_t)(n0 + s * 8 + srow) * ldk + (kk0) + skk,                    \
            &lB[(bufsel) * 8192 + s * 512]);                                         \
  }

template <int EPI, int OUTBF, int SPLITK>
__global__ __launch_bounds__(256) void gemm_mfma(const short* __restrict__ A,
                                                 const short* __restrict__ BT,
                                                 const float* __restrict__ bias,
                                                 float* __restrict__ Cf,
                                                 __hip_bfloat16* __restrict__ Cb,
                                                 int M, int N, int ldk) {
  __shared__ short lA[2 * 128 * 64];
  __shared__ short lB[2 * 128 * 64];
  const int tid = threadIdx.x;
  const int wid = tid >> 6, lane = tid & 63;

  // XCD-aware bijective block swizzle (grids here always have nwg % 8 == 0)
  const int nwg = gridDim.x * gridDim.y;
  const int wg = blockIdx.y * gridDim.x + blockIdx.x;
  const int qq = nwg >> 3, rr = nwg & 7;
  const int xcd = wg & 7, idx = wg >> 3;
  const int wg2 = (xcd < rr ? xcd * (qq + 1) : rr * (qq + 1) + (xcd - rr) * qq) + idx;
  const int bx = wg2 % gridDim.x, by = wg2 / gridDim.x;

  const int m0 = by * 128, n0 = bx * 128;
  const int wm = (wid >> 1) * 64, wn = (wid & 1) * 64;
  const int srow = lane >> 3;                         // row within 8-row slab
  const int skk = (((lane & 7) ^ (lane >> 3)) << 3);  // swizzled k offset (elems)

  int kstart = 0, klen = ldk;
  if (SPLITK > 1) {
    klen = ldk / SPLITK;
    kstart = blockIdx.z * klen;
    Cf += (size_t)blockIdx.z * M * N;
  }
  const int kend = kstart + klen;

  f32x4 acc[4][4] = {};

  GSTAGE(0, kstart);  // prologue: 8 loads/wave in flight
  int cur = 0;
  for (int k0 = kstart; k0 < kend; k0 += 64) {
    if (k0 + 64 < kend) {
      GSTAGE(cur ^ 1, k0 + 64);                         // +8 -> 16 in flight
      asm volatile("s_waitcnt vmcnt(8)" ::: "memory");  // oldest 8 (cur buf) done
    } else {
      asm volatile("s_waitcnt vmcnt(0)" ::: "memory");
    }
    asm volatile("s_barrier" ::: "memory");
    const short* bA = &lA[cur * 8192];
    const short* bB = &lB[cur * 8192];
#pragma unroll
    for (int kk = 0; kk < 2; ++kk) {
      const int krd = kk * 32 + (lane >> 4) * 8;
      const int rsel = lane & 15;
      const int kswz = krd ^ ((rsel & 7) << 3);  // same involution as store side
      bf16x8 af[4], bfr[4];
#pragma unroll
      for (int i = 0; i < 4; ++i) {
        af[i] = *(const bf16x8*)&bA[(wm + i * 16 + rsel) * 64 + kswz];
        bfr[i] = *(const bf16x8*)&bB[(wn + i * 16 + rsel) * 64 + kswz];
      }
#pragma unroll
      for (int i = 0; i < 4; ++i)
#pragma unroll
        for (int j = 0; j < 4; ++j)
          acc[i][j] = __builtin_amdgcn_mfma_f32_16x16x32_bf16(af[i], bfr[j], acc[i][j], 0, 0, 0);
    }
    // ds_read results are consumed by MFMA (compiler lgkmcnt) before here.
    asm volatile("s_barrier" ::: "memory");  // all waves done reading cur buf
    cur ^= 1;
  }

  const int crow = (lane >> 4) * 4;
  const int ccol = lane & 15;
#pragma unroll
  for (int j = 0; j < 4; ++j) {
    const int col = n0 + wn + j * 16 + ccol;
    const float bv = bias ? bias[col] : 0.f;
#pragma unroll
    for (int i = 0; i < 4; ++i) {
#pragma unroll
      for (int r = 0; r < 4; ++r) {
        float v = acc[i][j][r] + bv;
        const int row = m0 + wm + i * 16 + crow + r;
        if (EPI == EPI_QKV) {
          Cf[(size_t)row * QS + col] = (col < 2048) ? fmaxf(v, 0.f) : v;
        } else {
          if (EPI == EPI_RELU) v = fmaxf(v, 0.f);
          const size_t off = (size_t)row * N + col;
          if (OUTBF)
            Cb[off] = __float2bfloat16(v);
          else
            Cf[off] = v;
        }
      }
    }
  }
}

// ---------------------------------------------------------------------------
// amp/phi split-K reduce fused with activations and polar->cartesian:
//   amp = softplus(sum partials[.,c] + b_amp), phi = pi*tanh(sum + b_phi)
//   -> urh = bf16(amp*cos(phi)), uih = bf16(amp*sin(phi))
// part layout: [4][M][512] fp32 (cols 0..255 amp, 256..511 phi).
// ---------------------------------------------------------------------------
__global__ __launch_bounds__(256) void reduce_polar(const float* __restrict__ part,
                                                    const float* __restrict__ b_amp,
                                                    const float* __restrict__ b_phi,
                                                    __hip_bfloat16* __restrict__ outr,
                                                    __hip_bfloat16* __restrict__ outi) {
  const int idx = blockIdx.x * 256 + threadIdx.x;  // [0, M*NF)
  const int row = idx >> 8, c = idx & 255;
  const size_t MN = (size_t)Mm * 512;
  const size_t pa = (size_t)row * 512 + c;
  float a = part[pa] + part[pa + MN] + part[pa + 2 * MN] + part[pa + 3 * MN] + b_amp[c];
  float ph = part[pa + 256] + part[pa + 256 + MN] + part[pa + 256 + 2 * MN] +
             part[pa + 256 + 3 * MN] + b_phi[c];
  a = (a > 0.f) ? (a + log1pf(expf(-a))) : log1pf(expf(a));
  ph = M_PI_F * tanhf(ph);
  float s, co;
  sincosf(ph, &s, &co);
  outr[idx] = __float2bfloat16(a * co);
  outi[idx] = __float2bfloat16(a * s);
}

// ---------------------------------------------------------------------------
// Fused transpose-cast of all 8 weight matrices: W[K,N] f32 -> WT[N,K] bf16.
// ---------------------------------------------------------------------------
struct TCDesc {
  const float* src[8];
  __hip_bfloat16* dst[8];
};

__global__ __launch_bounds__(256) void transpose_cast_all(TCDesc d) {
  constexpr int KS[8] = {1024, 1024, 768, 1024, 1024, 1024, 1024, 4096};
  constexpr int NS[8] = {256, 256, 1024, 1024, 1024, 1024, 4096, 1024};
  constexpr int CUM[9] = {0, 256, 512, 1280, 2304, 3328, 4352, 8448, 12544};
  __shared__ float tile[32][33];
  const int bid = blockIdx.x;
  int w = 0;
#pragma unroll
  for (int i = 0; i < 8; ++i)
    if (bid >= CUM[i + 1]) w = i + 1;
  const int tlocal = bid - CUM[w];
  const int K = KS[w], N = NS[w];
  const int tilesN = N / 32;
  const int bk = (tlocal / tilesN) * 32, bn = (tlocal % tilesN) * 32;
  const float* W = d.src[w];
  __hip_bfloat16* WT = d.dst[w];
  const int tx = threadIdx.x & 31, ty = threadIdx.x >> 5;  // 32x8
#pragma unroll
  for (int r = 0; r < 32; r += 8) tile[ty + r][tx] = W[(size_t)(bk + ty + r) * N + bn + tx];
  __syncthreads();
#pragma unroll
  for (int r = 0; r < 32; r += 8)
    WT[(size_t)(bn + ty + r) * K + bk + tx] = __float2bfloat16(tile[tx][ty + r]);
}

// ---------------------------------------------------------------------------
// x: f32 -> bf16 cast (row-major, layout preserved)
// ---------------------------------------------------------------------------
__global__ __launch_bounds__(256) void cast_x(const float* __restrict__ x,
                                              __hip_bfloat16* __restrict__ xb) {
  const int i = (blockIdx.x * 256 + threadIdx.x) * 4;
  const float4 v = *(const float4*)&x[i];
  xb[i + 0] = __float2bfloat16(v.x);
  xb[i + 1] = __float2bfloat16(v.y);
  xb[i + 2] = __float2bfloat16(v.z);
  xb[i + 3] = __float2bfloat16(v.w);
}

// ---------------------------------------------------------------------------
// Sequential complex resonator recurrence; writes feat bf16 [B,T,3*NF].
// TIME-CHUNK PARALLEL (r6): contraction >= sigmoid(2.0)=0.881/step makes a
// 128-step warm-up from X=0 exact to below bf16 quantization. 64 blocks x
// 64 lanes; register double-buffer (P=16) keeps ~4KB/wave in flight.
// ---------------------------------------------------------------------------
static constexpr int RES_P = 16;
static constexpr int RES_TC = 128;  // chunk length
static constexpr int RES_W = 128;   // warm-up length

#define RES_LOAD(buf_r, buf_i, tg)                                        \
  if ((tg) < cend) {                                                      \
    _Pragma("unroll") for (int i = 0; i < RES_P; ++i) {                   \
      buf_r[i] = __bfloat162float(ur[bbase + (size_t)((tg) + i) * NFf]);  \
      buf_i[i] = __bfloat162float(ui[bbase + (size_t)((tg) + i) * NFf]);  \
    }                                                                     \
  }

#define RES_STEP(buf_r, buf_i, tg)                                      \
  {                                                                      \
    const bool wr_ = (tg) >= cstart;                                     \
    _Pragma("unroll") for (int i = 0; i < RES_P; ++i) {                  \
      const float pr = fmaf(ar, Xr, fmaf(-ai, Xi, buf_r[i]));            \
      const float pim = fmaf(ar, Xi, fmaf(ai, Xr, buf_i[i]));            \
      const float mag = __builtin_amdgcn_sqrtf(fmaf(pr, pr, pim * pim)); \
      const float g = __builtin_amdgcn_rcpf(1.f + __expf(th - mag));     \
      Xr = pr * g;                                                       \
      Xi = pim * g;                                                      \
      if (wr_) {                                                         \
        const size_t fb = ((size_t)b * Tt + (tg) + i) * (3 * NFf);       \
        featb[fb + f] = __float2bfloat16(Xr);                            \
        featb[fb + NFf + f] = __float2bfloat16(Xi);                      \
        featb[fb + 2 * NFf + f] = __float2bfloat16(mag * g);             \
      }                                                                  \
    }                                                                    \
  }

__global__ __launch_bounds__(64) void resonator_scan(const __hip_bfloat16* __restrict__ ur,
                                                     const __hip_bfloat16* __restrict__ ui,
                                                     const float* __restrict__ omega,
                                                     const float* __restrict__ ret_logit,
                                                     const float* __restrict__ theta,
                                                     __hip_bfloat16* __restrict__ featb) {
  const int bid = blockIdx.x;  // 64 blocks: (b:2, fs:4, tc:8)
  const int tc = bid & 7;
  const int fs = (bid >> 3) & 3;
  const int b = bid >> 5;
  const int f = fs * 64 + threadIdx.x;
  const int cstart = tc * RES_TC;
  const int cend = cstart + RES_TC;
  const int tbeg = (cstart >= RES_W) ? cstart - RES_W : 0;

  const float dec = 1.f / (1.f + __expf(-ret_logit[f]));
  float so, co;
  sincosf(omega[f], &so, &co);
  const float ar = dec * co, ai = dec * so;
  const float th = theta[f];
  const size_t bbase = (size_t)b * Tt * NFf + f;
  float Xr = 0.f, Xi = 0.f;
  float Ar[RES_P], Ai[RES_P], Br[RES_P], Bi[RES_P];
  RES_LOAD(Ar, Ai, tbeg);
  for (int t0 = tbeg; t0 < cend; t0 += 2 * RES_P) {
    RES_LOAD(Br, Bi, t0 + RES_P);
    RES_STEP(Ar, Ai, t0);
    RES_LOAD(Ar, Ai, t0 + 2 * RES_P);
    RES_STEP(Br, Bi, t0 + RES_P);
  }
}

// ---------------------------------------------------------------------------
// Attention phase A: per-chunk KV outer-product sums and k-sums.
// q/k/v live in the fused qkv buffer (row stride QS=3072).
// ---------------------------------------------------------------------------
__global__ __launch_bounds__(256) void attn_chunk_kv(const float* __restrict__ k,
                                                     const float* __restrict__ v,
                                                     float* __restrict__ S,
                                                     float* __restrict__ Ksum) {
  __shared__ float Ks[64][68], Vs[64][68];
  const int g = blockIdx.x;
  const int j = g & (NCHK - 1), bh = g >> 4;
  const int b = bh >> 4, h = bh & (Hh - 1);
  const int tid = threadIdx.x;
  const size_t rowbase = (size_t)(b * Tt + j * CHK) * QS + h * DHh;
  for (int l = tid; l < 4096; l += 256) {
    const int s = l >> 6, d = l & 63;
    Ks[s][d] = k[rowbase + (size_t)s * QS + d];
    Vs[s][d] = v[rowbase + (size_t)s * QS + d];
  }
  __syncthreads();
  const int d0 = tid & 63, eb = tid >> 6, e0 = eb * 16;
  float4 acc4[4] = {};
  float ks = 0.f;
  for (int s = 0; s < 64; ++s) {
    const float kd = Ks[s][d0];
    ks += kd;
#pragma unroll
    for (int i = 0; i < 4; ++i) {
      const float4 v4 = *(const float4*)&Vs[s][e0 + 4 * i];
      acc4[i].x = fmaf(kd, v4.x, acc4[i].x);
      acc4[i].y = fmaf(kd, v4.y, acc4[i].y);
      acc4[i].z = fmaf(kd, v4.z, acc4[i].z);
      acc4[i].w = fmaf(kd, v4.w, acc4[i].w);
    }
  }
  float* Sg = S + (size_t)g * 4096 + (size_t)d0 * 64 + e0;
#pragma unroll
  for (int i = 0; i < 4; ++i) *(float4*)&Sg[4 * i] = acc4[i];
  if (eb == 0) Ksum[(size_t)g * 64 + d0] = ks;
}

// ---------------------------------------------------------------------------
// Attention phase B: in-place EXCLUSIVE prefix over the 16 chunks per (b,h).
// ---------------------------------------------------------------------------
__global__ __launch_bounds__(256) void attn_prefix(float* __restrict__ S,
                                                   float* __restrict__ Ksum) {
  const int bh = blockIdx.x;
  const int tid = threadIdx.x;
  for (int r = 0; r < 16; ++r) {
    const int de = r * 256 + tid;
    float run = 0.f;
    size_t p = (size_t)bh * (NCHK * 4096) + de;
    for (int j = 0; j < NCHK; ++j, p += 4096) {
      const float tmp = S[p];
      S[p] = run;
      run += tmp;
    }
  }
  if (tid < 64) {
    float run = 0.f;
    size_t p = (size_t)bh * (NCHK * 64) + tid;
    for (int j = 0; j < NCHK; ++j, p += 64) {
      const float tmp = Ksum[p];
      Ksum[p] = run;
      run += tmp;
    }
  }
}

// ---------------------------------------------------------------------------
// Attention phase C: per-chunk output (q/k/v strided QS; y is [B,T,H,DH]).
// ---------------------------------------------------------------------------
__global__ __launch_bounds__(256) void attn_out(const float* __restrict__ q,
                                                const float* __restrict__ k,
                                                const float* __restrict__ v,
                                                const float* __restrict__ S,
                                                const float* __restrict__ Ksum,
                                                float* __restrict__ y) {
  __shared__ float Qt[64][65];
  __shared__ float KVP[64][68];
  __shared__ float At[64][65];
  const int g = blockIdx.x;
  const int j = g & (NCHK - 1), bh = g >> 4;
  const int b = bh >> 4, h = bh & (Hh - 1);
  const int tid = threadIdx.x;
  const size_t rowbase = (size_t)(b * Tt + j * CHK) * QS + h * DHh;
  const size_t ybase = (((size_t)b * Tt + j * CHK) * Hh + h) * DHh;
  for (int l = tid; l < 4096; l += 256) {
    const int s = l >> 6, d = l & 63;
    Qt[d][s] = q[rowbase + (size_t)s * QS + d];
    KVP[s][d] = k[rowbase + (size_t)s * QS + d];
  }
  __syncthreads();
  const int t = tid >> 2, sg = tid & 3;
  const float* pk = Ksum + (size_t)g * 64;
  // --- stage 1: masked scores + denominator ---
  float adot[16] = {};
  float qpk = 0.f;
  for (int c = 0; c < 16; ++c) {
    const float q0 = Qt[4 * c + 0][t], q1 = Qt[4 * c + 1][t];
    const float q2 = Qt[4 * c + 2][t], q3 = Qt[4 * c + 3][t];
    const float4 pk4 = *(const float4*)&pk[4 * c];
    qpk = fmaf(q0, pk4.x, fmaf(q1, pk4.y, fmaf(q2, pk4.z, fmaf(q3, pk4.w, qpk))));
#pragma unroll
    for (int i = 0; i < 16; ++i) {
      const float4 k4 = *(const float4*)&KVP[sg * 16 + i][4 * c];
      adot[i] = fmaf(q0, k4.x, fmaf(q1, k4.y, fmaf(q2, k4.z, fmaf(q3, k4.w, adot[i]))));
    }
  }
  float rs = 0.f;
#pragma unroll
  for (int i = 0; i < 16; ++i) {
    if (sg * 16 + i > t) adot[i] = 0.f;
    rs += adot[i];
  }
  rs += __shfl_xor(rs, 1);
  rs += __shfl_xor(rs, 2);
  const float den = qpk + rs + 1e-6f;
  __syncthreads();  // all K reads complete
#pragma unroll
  for (int i = 0; i < 16; ++i) At[sg * 16 + i][t] = adot[i];
  for (int l = tid; l < 4096; l += 256) {  // overwrite K with V
    const int s = l >> 6, d = l & 63;
    KVP[s][d] = v[rowbase + (size_t)s * QS + d];
  }
  __syncthreads();
  // --- stage 2a: masked-score @ V ---
  const int e0 = sg * 16;
  float4 num[4] = {};
  for (int s = 0; s <= t; ++s) {
    const float av = At[s][t];
#pragma unroll
    for (int i = 0; i < 4; ++i) {
      const float4 v4 = *(const float4*)&KVP[s][e0 + 4 * i];
      num[i].x = fmaf(av, v4.x, num[i].x);
      num[i].y = fmaf(av, v4.y, num[i].y);
      num[i].z = fmaf(av, v4.z, num[i].z);
      num[i].w = fmaf(av, v4.w, num[i].w);
    }
  }
  __syncthreads();  // all V reads complete
  const float* Pg = S + (size_t)g * 4096;
  for (int l = tid; l < 4096; l += 256) KVP[l >> 6][l & 63] = Pg[l];
  __syncthreads();
  // --- stage 2b: Q @ P ---
  for (int d = 0; d < 64; ++d) {
    const float qd = Qt[d][t];
#pragma unroll
    for (int i = 0; i < 4; ++i) {
      const float4 p4 = *(const float4*)&KVP[d][e0 + 4 * i];
      num[i].x = fmaf(qd, p4.x, num[i].x);
      num[i].y = fmaf(qd, p4.y, num[i].y);
      num[i].z = fmaf(qd, p4.z, num[i].z);
      num[i].w = fmaf(qd, p4.w, num[i].w);
    }
  }
  const float inv = 1.f / den;
  float* yg = y + ybase + (size_t)t * (Hh * DHh) + e0;
#pragma unroll
  for (int i = 0; i < 4; ++i) {
    float4 o;
    o.x = num[i].x * inv;
    o.y = num[i].y * inv;
    o.z = num[i].z * inv;
    o.w = num[i].w * inv;
    *(float4*)&yg[4 * i] = o;
  }
}

// ---------------------------------------------------------------------------
// Per-head layernorm over DH=64, output bf16 [B,T,D].
// ---------------------------------------------------------------------------
__global__ __launch_bounds__(256) void ln_head(const float* __restrict__ y,
                                               const float* __restrict__ w,
                                               const float* __restrict__ bsh,
                                               __hip_bfloat16* __restrict__ out) {
  const int tid = threadIdx.x;
  const int e = tid & 63;
  const int r = blockIdx.x * 4 + (tid >> 6);
  const int h = r & (Hh - 1);
  const float val = y[(size_t)r * DHh + e];
  float s = val;
#pragma unroll
  for (int o = 1; o < 64; o <<= 1) s += __shfl_xor(s, o);
  const float mean = s * (1.f / 64.f);
  const float dv = val - mean;
  float s2 = dv * dv;
#pragma unroll
  for (int o = 1; o < 64; o <<= 1) s2 += __shfl_xor(s2, o);
  const float var = s2 * (1.f / 64.f);
  const float res = dv * rsqrtf(var + 1e-5f) * w[h * DHh + e] + bsh[h * DHh + e];
  out[(size_t)r * DHh + e] = __float2bfloat16(res);
}

// ---------------------------------------------------------------------------
// Fused FFN2-reduce + bias + relu + residual + final layernorm over D=1024.
// ---------------------------------------------------------------------------
__global__ __launch_bounds__(256) void final_ln(const float* __restrict__ x,
                                                const float* __restrict__ part,
                                                const float* __restrict__ b2,
                                                const float* __restrict__ w,
                                                const float* __restrict__ bb,
                                                float* __restrict__ out) {
  __shared__ float r1[4], r2[4];
  const int row = blockIdx.x;
  const int tid = threadIdx.x;
  const size_t off = (size_t)row * Dd + tid * 4;
  const size_t MN = (size_t)Mm * Dd;
  const float4 p0 = *(const float4*)&part[off];
  const float4 p1 = *(const float4*)&part[off + MN];
  const float4 bv = *(const float4*)&b2[tid * 4];
  const float4 xa = *(const float4*)&x[off];
  float z[4];
  z[0] = xa.x + fmaxf(p0.x + p1.x + bv.x, 0.f);
  z[1] = xa.y + fmaxf(p0.y + p1.y + bv.y, 0.f);
  z[2] = xa.z + fmaxf(p0.z + p1.z + bv.z, 0.f);
  z[3] = xa.w + fmaxf(p0.w + p1.w + bv.w, 0.f);
  float s1 = z[0] + z[1] + z[2] + z[3];
  float s2 = z[0] * z[0] + z[1] * z[1] + z[2] * z[2] + z[3] * z[3];
#pragma unroll
  for (int o = 1; o < 64; o <<= 1) {
    s1 += __shfl_xor(s1, o);
    s2 += __shfl_xor(s2, o);
  }
  const int wid = tid >> 6;
  if ((tid & 63) == 0) {
    r1[wid] = s1;
    r2[wid] = s2;
  }
  __syncthreads();
  const float t1 = r1[0] + r1[1] + r1[2] + r1[3];
  const float t2 = r2[0] + r2[1] + r2[2] + r2[3];
  const float mu = t1 * (1.f / Dd);
  const float var = t2 * (1.f / Dd) - mu * mu;
  const float rsv = rsqrtf(var + 1e-5f);
  float4 o4;
  float* op = &o4.x;
#pragma unroll
  for (int jj = 0; jj < 4; ++jj) op[jj] = (z[jj] - mu) * rsv * w[tid * 4 + jj] + bb[tid * 4 + jj];
  *(float4*)&out[off] = o4;
}

// ---------------------------------------------------------------------------
extern "C" void kernel_launch(void* const* d_in, const int* in_sizes, int n_in,
                              void* d_out, int out_size, void* d_ws, size_t ws_size,
                              hipStream_t stream) {
  const float* x = (const float*)d_in[0];
  const float* W_amp = (const float*)d_in[1];
  const float* b_amp = (const float*)d_in[2];
  const float* W_phi = (const float*)d_in[3];
  const float* b_phi = (const float*)d_in[4];
  const float* omega = (const float*)d_in[5];
  const float* ret_logit = (const float*)d_in[6];
  const float* theta = (const float*)d_in[7];
  const float* W_feat = (const float*)d_in[8];
  const float* b_feat = (const float*)d_in[9];
  const float* Wq = (const float*)d_in[10];
  const float* Wk = (const float*)d_in[11];
  const float* Wv = (const float*)d_in[12];
  const float* lnh_w = (const float*)d_in[13];
  const float* lnh_b = (const float*)d_in[14];
  const float* W1 = (const float*)d_in[15];
  const float* b1 = (const float*)d_in[16];
  const float* W2 = (const float*)d_in[17];
  const float* b2 = (const float*)d_in[18];
  const float* ln_w = (const float*)d_in[19];
  const float* ln_b = (const float*)d_in[20];

  // ---- workspace bump allocator (256B aligned) ----
  char* p = (char*)d_ws;
  auto alloc = [&](size_t bytes) {
    char* r = p;
    p += (bytes + 255) & ~(size_t)255;
    return r;
  };
  __hip_bfloat16* xb = (__hip_bfloat16*)alloc((size_t)Mm * Dd * 2);  // later: featb
  __hip_bfloat16* urh = (__hip_bfloat16*)alloc((size_t)Mm * NFf * 2);  // bf16 Re(u)
  __hip_bfloat16* uih = (__hip_bfloat16*)alloc((size_t)Mm * NFf * 2);  // bf16 Im(u)
  __hip_bfloat16* WTamp = (__hip_bfloat16*)alloc((size_t)NFf * Dd * 2);  // +WTphi contiguous
  __hip_bfloat16* WTphi = (__hip_bfloat16*)alloc((size_t)NFf * Dd * 2);
  __hip_bfloat16* WTfeat = (__hip_bfloat16*)alloc((size_t)Dd * 3 * NFf * 2);
  __hip_bfloat16* WTq = (__hip_bfloat16*)alloc((size_t)Dd * Dd * 2);  // +k+v contiguous
  __hip_bfloat16* WTk = (__hip_bfloat16*)alloc((size_t)Dd * Dd * 2);
  __hip_bfloat16* WTv = (__hip_bfloat16*)alloc((size_t)Dd * Dd * 2);
  __hip_bfloat16* WT1 = (__hip_bfloat16*)alloc((size_t)Rr * Dd * 2);
  __hip_bfloat16* WT2 = (__hip_bfloat16*)alloc((size_t)Dd * Rr * 2);
  __hip_bfloat16* hb = (__hip_bfloat16*)alloc((size_t)Mm * Dd * 2);
  float* qkv = (float*)alloc((size_t)Mm * QS * 4);  // 24 MB; amp/phi partials pre-qkv,
                                                    // later yhb + f1b
  float* y = (float*)alloc((size_t)Mm * Dd * 4);    // 8 MB; later partial_ffn2[0]
  float* S = (float*)alloc((size_t)Bb * Hh * NCHK * 4096 * 4);  // 8 MB; later partial_ffn2[1]
  float* Ksum = (float*)alloc((size_t)Bb * Hh * NCHK * 64 * 4);

  __hip_bfloat16* featb = xb;
  const float* q = qkv;
  const float* k = qkv + 1024;
  const float* v = qkv + 2048;
  // amp/phi split-K=4 partials [4][M][512] = 16 MB in the (then-dead) qkv region
  float* pamp = qkv;
  __hip_bfloat16* yhb = (__hip_bfloat16*)qkv;                        // [M,1024] bf16 (4 MB)
  __hip_bfloat16* f1b = (__hip_bfloat16*)(qkv + (size_t)Mm * 1024);  // [M,4096] bf16 (16 MB)
  // FFN2 fp32 partials [2][M][1024] = 16 MB over y(8)+S(8): both dead after
  // ln_head / attn_out, disjoint from f1b and WT2 (r4's overlay raced WT2).
  float* partial = y;
  float* out = (float*)d_out;

  const dim3 blk(256);

  // 0: casts
  cast_x<<<dim3(Mm * Dd / 1024), blk, 0, stream>>>(x, xb);
  TCDesc tc;
  tc.src[0] = W_amp; tc.dst[0] = WTamp;
  tc.src[1] = W_phi; tc.dst[1] = WTphi;
  tc.src[2] = W_feat; tc.dst[2] = WTfeat;
  tc.src[3] = Wq; tc.dst[3] = WTq;
  tc.src[4] = Wk; tc.dst[4] = WTk;
  tc.src[5] = Wv; tc.dst[5] = WTv;
  tc.src[6] = W1; tc.dst[6] = WT1;
  tc.src[7] = W2; tc.dst[7] = WT2;
  transpose_cast_all<<<dim3(12544), blk, 0, stream>>>(tc);

  // 1: fused amp/phi projection, split-K=4 (grid 256 = full machine), then
  //    fused reduce + softplus/tanh + polar -> bf16 u
  gemm_mfma<EPI_NONE, 0, 4><<<dim3(512 / 128, Mm / 128, 4), blk, 0, stream>>>(
      (const short*)xb, (const short*)WTamp, nullptr, pamp, nullptr, Mm, 512, Dd);
  reduce_polar<<<dim3(Mm * NFf / 256), blk, 0, stream>>>(pamp, b_amp, b_phi, urh, uih);

  // 2: resonator scan -> feat (bf16); 64 blocks x 64 lanes, time-chunked
  resonator_scan<<<dim3(64), dim3(64), 0, stream>>>(urh, uih, omega, ret_logit, theta, featb);

  // 3: feat projection -> h (bf16)
  gemm_mfma<EPI_RELU, 1, 0><<<dim3(Dd / 128, Mm / 128), blk, 0, stream>>>(
      (const short*)featb, (const short*)WTfeat, b_feat, nullptr, hb, Mm, Dd, 3 * NFf);

  // 4: fused q,k,v projection (N=3072 -> qkv buffer, relu on q,k only)
  gemm_mfma<EPI_QKV, 0, 0><<<dim3(QS / 128, Mm / 128), blk, 0, stream>>>(
      (const short*)hb, (const short*)WTq, nullptr, qkv, nullptr, Mm, QS, Dd);

  // 5: chunked causal linear attention
  attn_chunk_kv<<<dim3(Bb * Hh * NCHK), blk, 0, stream>>>(k, v, S, Ksum);
  attn_prefix<<<dim3(Bb * Hh), blk, 0, stream>>>(S, Ksum);
  attn_out<<<dim3(Bb * Hh * NCHK), blk, 0, stream>>>(q, k, v, S, Ksum, y);

  // 6: per-head layernorm -> bf16 (qkv dead; yhb overlays it)
  ln_head<<<dim3(Bb * Tt * Hh / 4), blk, 0, stream>>>(y, lnh_w, lnh_b, yhb);

  // 7: FFN1 -> f1b (bf16)
  gemm_mfma<EPI_RELU, 1, 0><<<dim3(Rr / 128, Mm / 128), blk, 0, stream>>>(
      (const short*)yhb, (const short*)WT1, b1, nullptr, f1b, Mm, Rr, Dd);

  // 8: FFN2 split-K=2 -> partials over y+S (grid = 256 blocks = full machine)
  gemm_mfma<EPI_NONE, 0, 2><<<dim3(Dd / 128, Mm / 128, 2), blk, 0, stream>>>(
      (const short*)f1b, (const short*)WT2, nullptr, partial, nullptr, Mm, Dd, Rr);

  // 9: fused reduce + bias + relu + residual + final layernorm
  final_ln<<<dim3(Mm), blk, 0, stream>>>(x, partial, b2, ln_w, ln_b, out);
}